// Round 4
// baseline (141.623 us; speedup 1.0000x reference)
//
#include <hip/hip_runtime.h>
#include <hip/hip_bf16.h>
#include <hip/hip_cooperative_groups.h>

namespace cg = cooperative_groups;

#define EPS_F 1e-8f
#define MIN_THRESH_F 0.1f

// Single cooperative kernel: gather + per-row cosine + masked mean.
// One row per HALF-wave (32 lanes x 4 float4 = 512 floats = D).
// d_ws: float2 partials[gridDim.x], written unconditionally every call.
// grid.sync() then block 0 reduces partials -> out. No atomics, no memset.

__global__ __launch_bounds__(256, 4) void cosloss_fused(
    const float* __restrict__ a, const float* __restrict__ b,
    const int* __restrict__ labels, int N, float2* __restrict__ partials,
    float* __restrict__ out)
{
    const int lane = threadIdx.x & 63;
    const int wave = threadIdx.x >> 6;      // 0..3
    const int sub  = lane & 31;             // lane within half-wave
    const int half = lane >> 5;             // 0 or 1
    const int wid  = (blockIdx.x << 2) + wave;
    const int totalWaves = gridDim.x << 2;  // 4096

    float total = 0.0f, cnt = 0.0f;

    for (int rb = wid * 2; rb < N; rb += totalWaves * 2) {
        const int r = rb + half;
        const bool valid = r < N;
        const int label = labels[valid ? r : 0];

        const char* pa = (const char*)a + ((long long)label << 11) + (sub << 4);
        const char* pb = (const char*)b + ((long long)label << 11) + (sub << 4);

        float4 a0 = *(const float4*)(pa);
        float4 a1 = *(const float4*)(pa + 512);
        float4 a2 = *(const float4*)(pa + 1024);
        float4 a3 = *(const float4*)(pa + 1536);
        float4 b0 = *(const float4*)(pb);
        float4 b1 = *(const float4*)(pb + 512);
        float4 b2 = *(const float4*)(pb + 1024);
        float4 b3 = *(const float4*)(pb + 1536);

        float ip = a0.x*b0.x + a0.y*b0.y + a0.z*b0.z + a0.w*b0.w
                 + a1.x*b1.x + a1.y*b1.y + a1.z*b1.z + a1.w*b1.w
                 + a2.x*b2.x + a2.y*b2.y + a2.z*b2.z + a2.w*b2.w
                 + a3.x*b3.x + a3.y*b3.y + a3.z*b3.z + a3.w*b3.w;
        float s1 = a0.x*a0.x + a0.y*a0.y + a0.z*a0.z + a0.w*a0.w
                 + a1.x*a1.x + a1.y*a1.y + a1.z*a1.z + a1.w*a1.w
                 + a2.x*a2.x + a2.y*a2.y + a2.z*a2.z + a2.w*a2.w
                 + a3.x*a3.x + a3.y*a3.y + a3.z*a3.z + a3.w*a3.w;
        float s2 = b0.x*b0.x + b0.y*b0.y + b0.z*b0.z + b0.w*b0.w
                 + b1.x*b1.x + b1.y*b1.y + b1.z*b1.z + b1.w*b1.w
                 + b2.x*b2.x + b2.y*b2.y + b2.z*b2.z + b2.w*b2.w
                 + b3.x*b3.x + b3.y*b3.y + b3.z*b3.z + b3.w*b3.w;

        // 5-step butterfly within the 32-lane half
        #pragma unroll
        for (int off = 16; off >= 1; off >>= 1) {
            ip += __shfl_xor(ip, off);
            s1 += __shfl_xor(s1, off);
            s2 += __shfl_xor(s2, off);
        }

        if (sub == 0 && valid) {
            float c = ip / fmaxf(sqrtf(s1) * sqrtf(s2), EPS_F);
            if (c >= MIN_THRESH_F) { total += c; cnt += 1.0f; }
        }
    }

    // block-level reduce -> one partial per block
    __shared__ float st[8], sc[8];
    if (sub == 0) { st[(wave << 1) + half] = total; sc[(wave << 1) + half] = cnt; }
    __syncthreads();
    if (threadIdx.x == 0) {
        float t = 0.0f, c = 0.0f;
        #pragma unroll
        for (int i = 0; i < 8; ++i) { t += st[i]; c += sc[i]; }
        partials[blockIdx.x] = make_float2(t, c);
        __threadfence();   // make partial visible device-wide before barrier
    }

    cg::this_grid().sync();

    if (blockIdx.x == 0) {
        // 1024 partials = 512 float4; 256 threads x 2 iterations
        const float4* p4 = (const float4*)partials;
        float t = 0.0f, c = 0.0f;
        #pragma unroll
        for (int k = 0; k < 2; ++k) {
            float4 p = p4[threadIdx.x + (k << 8)];
            t += p.x + p.z;
            c += p.y + p.w;
        }
        #pragma unroll
        for (int off = 32; off >= 1; off >>= 1) {
            t += __shfl_xor(t, off);
            c += __shfl_xor(c, off);
        }
        __shared__ float ft[4], fc[4];
        if (lane == 0) { ft[wave] = t; fc[wave] = c; }
        __syncthreads();
        if (threadIdx.x == 0) {
            float T = ft[0] + ft[1] + ft[2] + ft[3];
            float C = fc[0] + fc[1] + fc[2] + fc[3];
            if (C < 1.0f) C = 1.0f;
            out[0] = T / C;
        }
    }
}

extern "C" void kernel_launch(void* const* d_in, const int* in_sizes, int n_in,
                              void* d_out, int out_size, void* d_ws, size_t ws_size,
                              hipStream_t stream)
{
    const float* a      = (const float*)d_in[0];
    const float* b      = (const float*)d_in[1];
    const int*   labels = (const int*)d_in[2];
    int N = in_sizes[2];

    float2* partials = (float2*)d_ws;
    float*  out      = (float*)d_out;

    void* args[] = {(void*)&a, (void*)&b, (void*)&labels, (void*)&N,
                    (void*)&partials, (void*)&out};
    // 1024 blocks = 4 blocks/CU x 256 CUs co-resident (launch_bounds(256,4)
    // caps VGPR at 128 -> 4 waves/SIMD), satisfying cooperative co-residency.
    hipLaunchCooperativeKernel((void*)cosloss_fused, dim3(1024), dim3(256),
                               args, 0, stream);
}

// Round 5
// 18.946 us; speedup vs baseline: 7.4752x; 7.4752x over previous
//
#include <hip/hip_runtime.h>
#include <hip/hip_bf16.h>

#define EPS_F 1e-8f
#define MIN_THRESH_F 0.1f

// Two kernels (cooperative fusion regressed 7x in R4 -- grid.sync spin).
// One row per HALF-wave (32 lanes x 4 float4 = 512 floats = D).
// All 8 loads issued into distinct registers and pinned live with an empty
// asm before any FMA: R4's VGPR_Count=28 proved the compiler otherwise
// serializes the loads into a load->fma->load dependency chain.
// d_ws: float2 partials[blocks], written unconditionally -> deterministic,
// no memset, no atomics.

__global__ __launch_bounds__(256) void cosloss_main(
    const float* __restrict__ a, const float* __restrict__ b,
    const int* __restrict__ labels, int N, float2* __restrict__ partials)
{
    const int lane = threadIdx.x & 63;
    const int wave = threadIdx.x >> 6;      // 0..3
    const int sub  = lane & 31;             // lane within half-wave
    const int half = lane >> 5;             // 0 or 1
    const int hwid = (blockIdx.x << 3) + (wave << 1) + half;  // half-wave id
    const int nhw  = gridDim.x << 3;        // total half-waves (16384)

    float total = 0.0f, cnt = 0.0f;

    for (int r = hwid; r < N; r += nhw) {   // trip count 1 for N=16384
        const int label = labels[r];
        const char* pa = (const char*)a + ((long long)label << 11) + (sub << 4);
        const char* pb = (const char*)b + ((long long)label << 11) + (sub << 4);

        float4 A0 = *(const float4*)(pa);
        float4 A1 = *(const float4*)(pa + 512);
        float4 A2 = *(const float4*)(pa + 1024);
        float4 A3 = *(const float4*)(pa + 1536);
        float4 B0 = *(const float4*)(pb);
        float4 B1 = *(const float4*)(pb + 512);
        float4 B2 = *(const float4*)(pb + 1024);
        float4 B3 = *(const float4*)(pb + 1536);

        // Pin all 8 loads live before any FMA: forces distinct dest registers
        // so the 8 global_load_dwordx4 issue back-to-back (one vmcnt wait)
        // instead of a serialized load->fma->load chain (R4: VGPR=28).
        asm volatile("" ::
            "v"(A0.x), "v"(A0.w), "v"(A1.x), "v"(A1.w),
            "v"(A2.x), "v"(A2.w), "v"(A3.x), "v"(A3.w),
            "v"(B0.x), "v"(B0.w), "v"(B1.x), "v"(B1.w),
            "v"(B2.x), "v"(B2.w), "v"(B3.x), "v"(B3.w));

        float ip = A0.x*B0.x + A0.y*B0.y + A0.z*B0.z + A0.w*B0.w
                 + A1.x*B1.x + A1.y*B1.y + A1.z*B1.z + A1.w*B1.w
                 + A2.x*B2.x + A2.y*B2.y + A2.z*B2.z + A2.w*B2.w
                 + A3.x*B3.x + A3.y*B3.y + A3.z*B3.z + A3.w*B3.w;
        float s1 = A0.x*A0.x + A0.y*A0.y + A0.z*A0.z + A0.w*A0.w
                 + A1.x*A1.x + A1.y*A1.y + A1.z*A1.z + A1.w*A1.w
                 + A2.x*A2.x + A2.y*A2.y + A2.z*A2.z + A2.w*A2.w
                 + A3.x*A3.x + A3.y*A3.y + A3.z*A3.z + A3.w*A3.w;
        float s2 = B0.x*B0.x + B0.y*B0.y + B0.z*B0.z + B0.w*B0.w
                 + B1.x*B1.x + B1.y*B1.y + B1.z*B1.z + B1.w*B1.w
                 + B2.x*B2.x + B2.y*B2.y + B2.z*B2.z + B2.w*B2.w
                 + B3.x*B3.x + B3.y*B3.y + B3.z*B3.z + B3.w*B3.w;

        // 5-step butterfly within the 32-lane half
        #pragma unroll
        for (int off = 16; off >= 1; off >>= 1) {
            ip += __shfl_xor(ip, off);
            s1 += __shfl_xor(s1, off);
            s2 += __shfl_xor(s2, off);
        }

        if (sub == 0) {
            float c = ip / fmaxf(sqrtf(s1) * sqrtf(s2), EPS_F);
            if (c >= MIN_THRESH_F) { total += c; cnt += 1.0f; }
        }
    }

    __shared__ float st[8], sc[8];
    if (sub == 0) { st[(wave << 1) + half] = total; sc[(wave << 1) + half] = cnt; }
    __syncthreads();
    if (threadIdx.x == 0) {
        float t = 0.0f, c = 0.0f;
        #pragma unroll
        for (int i = 0; i < 8; ++i) { t += st[i]; c += sc[i]; }
        partials[blockIdx.x] = make_float2(t, c);
    }
}

__global__ __launch_bounds__(256) void cosloss_final(
    const float4* __restrict__ partials4, int M4, float* __restrict__ out)
{
    float t = 0.0f, c = 0.0f;
    for (int i = threadIdx.x; i < M4; i += 256) {
        float4 p = partials4[i];           // two float2 partials
        t += p.x + p.z;
        c += p.y + p.w;
    }
    #pragma unroll
    for (int off = 32; off >= 1; off >>= 1) {
        t += __shfl_xor(t, off);
        c += __shfl_xor(c, off);
    }
    __shared__ float st[4], sc[4];
    const int lane = threadIdx.x & 63, w = threadIdx.x >> 6;
    if (lane == 0) { st[w] = t; sc[w] = c; }
    __syncthreads();
    if (threadIdx.x == 0) {
        float T = st[0] + st[1] + st[2] + st[3];
        float C = sc[0] + sc[1] + sc[2] + sc[3];
        if (C < 1.0f) C = 1.0f;
        out[0] = T / C;
    }
}

extern "C" void kernel_launch(void* const* d_in, const int* in_sizes, int n_in,
                              void* d_out, int out_size, void* d_ws, size_t ws_size,
                              hipStream_t stream)
{
    const float* a      = (const float*)d_in[0];
    const float* b      = (const float*)d_in[1];
    const int*   labels = (const int*)d_in[2];
    const int N = in_sizes[2];

    float2* partials = (float2*)d_ws;

    int blocks = (N + 7) / 8;               // one row per half-wave
    if (blocks > 2048) blocks = 2048;
    cosloss_main<<<blocks, 256, 0, stream>>>(a, b, labels, N, partials);
    cosloss_final<<<1, 256, 0, stream>>>((const float4*)partials, blocks / 2,
                                         (float*)d_out);
}